// Round 1
// baseline (1438.987 us; speedup 1.0000x reference)
//
#include <hip/hip_runtime.h>

#define S_LEN 1024
#define BATCH 4096
#define NIN 64
#define NHID 128
#define BT 16      // batch rows per block
#define NPAD 136   // padded h row stride (bf16 elems): 272B = 68 dwords == 4 mod 32 banks

typedef __attribute__((ext_vector_type(8))) short bf16x8;
typedef __attribute__((ext_vector_type(4))) float f32x4;
typedef __attribute__((ext_vector_type(4))) short s16x4;

__device__ __forceinline__ unsigned short f2bf(float f) {
    union { float f; unsigned u; } v; v.f = f;
    unsigned r = v.u + 0x7FFFu + ((v.u >> 16) & 1u);   // RNE
    return (unsigned short)(r >> 16);
}
__device__ __forceinline__ float bf2f(unsigned short h) {
    union { float f; unsigned u; } v; v.u = ((unsigned)h) << 16;
    return v.f;
}
__device__ __forceinline__ float tanh_fast(float z) {
    // tanh(z) = (e^{2z}-1)/(e^{2z}+1); e^{2z} = 2^(z*2/ln2)
    float u = __builtin_amdgcn_exp2f(z * 2.885390081777927f);
    return (u - 1.0f) * __builtin_amdgcn_rcpf(u + 1.0f);
}

__global__ __launch_bounds__(512, 2)
void rnn_kernel(const float* __restrict__ x,
                const float* __restrict__ W_ih,
                const float* __restrict__ b_ih,
                const float* __restrict__ W_hh,
                const float* __restrict__ b_hh,
                float* __restrict__ out)
{
    __shared__ short hbuf[2][BT][NPAD];

    const int tid  = threadIdx.x;
    const int w    = tid >> 6;    // wave 0..7, owns hidden rows [16w,16w+16)
    const int lane = tid & 63;
    const int col  = lane & 15;   // batch index within tile (MFMA B-op col / C col)
    const int kg   = lane >> 4;   // k-group 0..3

    const int b0 = blockIdx.x * BT;

    // zero h double-buffer (h_0 = 0)
    for (int i = tid; i < 2 * BT * NPAD; i += 512) ((short*)hbuf)[i] = 0;

    // ---- persistent weight fragments (MFMA A-operand):
    // A[m][k]: m = lane&15 -> W row n = 16w+col ; k = 32*kk + 8*kg + j (contiguous)
    // split W = hi(bf16) + lo(bf16 of residual) for ~fp32-accurate weights
    const int nrow = 16 * w + col;
    bf16x8 wih_h[2], wih_l[2], whh_h[4], whh_l[4];
    #pragma unroll
    for (int kk = 0; kk < 2; ++kk) {
        const float* p = W_ih + nrow * NIN + kk * 32 + kg * 8;
        #pragma unroll
        for (int j = 0; j < 8; ++j) {
            float f = p[j];
            unsigned short hi = f2bf(f);
            wih_h[kk][j] = (short)hi;
            wih_l[kk][j] = (short)f2bf(f - bf2f(hi));
        }
    }
    #pragma unroll
    for (int kk = 0; kk < 4; ++kk) {
        const float* p = W_hh + nrow * NHID + kk * 32 + kg * 8;
        #pragma unroll
        for (int j = 0; j < 8; ++j) {
            float f = p[j];
            unsigned short hi = f2bf(f);
            whh_h[kk][j] = (short)hi;
            whh_l[kk][j] = (short)f2bf(f - bf2f(hi));
        }
    }

    // bias for this lane's 4 output hidden units n = 16w + 4kg + i
    f32x4 biasv;
    {
        f32x4 bi = *(const f32x4*)(b_ih + 16 * w + 4 * kg);
        f32x4 bh = *(const f32x4*)(b_hh + 16 * w + 4 * kg);
        biasv = bi + bh;
    }

    // x B-operand: lane reads x_t[b=col][k = 32*kk + 8*kg + j] -> 2x 32B chunks
    const float* xlane = x + ((size_t)b0 + col) * NIN + kg * 8;

    // 2-deep software prefetch pipeline (two register stages)
    f32x4 a0, a1, a2, a3, c0, c1, c2, c3;
    {
        const float* p = xlane;                      // t = 0
        a0 = *(const f32x4*)(p);      a1 = *(const f32x4*)(p + 4);
        a2 = *(const f32x4*)(p + 32); a3 = *(const f32x4*)(p + 36);
        p = xlane + (size_t)BATCH * NIN;             // t = 1
        c0 = *(const f32x4*)(p);      c1 = *(const f32x4*)(p + 4);
        c2 = *(const f32x4*)(p + 32); c3 = *(const f32x4*)(p + 36);
    }
    __syncthreads();

    auto step = [&](int t, f32x4& r0, f32x4& r1, f32x4& r2, f32x4& r3) {
        // pack x fragments (consume stage), then reuse regs for t+2 prefetch
        bf16x8 xf0, xf1;
        #pragma unroll
        for (int j = 0; j < 4; ++j) {
            xf0[j]     = (short)f2bf(r0[j]);
            xf0[j + 4] = (short)f2bf(r1[j]);
            xf1[j]     = (short)f2bf(r2[j]);
            xf1[j + 4] = (short)f2bf(r3[j]);
        }
        if (t + 2 < S_LEN) {
            const float* p = xlane + (size_t)(t + 2) * BATCH * NIN;
            r0 = *(const f32x4*)(p);      r1 = *(const f32x4*)(p + 4);
            r2 = *(const f32x4*)(p + 32); r3 = *(const f32x4*)(p + 36);
        }

        // h B-operand fragments: lane reads h[b=col][32*kk + 8*kg ..+7] (16B, ds_read_b128)
        const short* hrow = &hbuf[t & 1][col][0];
        bf16x8 hf0 = *(const bf16x8*)(hrow + 0 * 32 + kg * 8);
        bf16x8 hf1 = *(const bf16x8*)(hrow + 1 * 32 + kg * 8);
        bf16x8 hf2 = *(const bf16x8*)(hrow + 2 * 32 + kg * 8);
        bf16x8 hf3 = *(const bf16x8*)(hrow + 3 * 32 + kg * 8);

        f32x4 acc = biasv;
        acc = __builtin_amdgcn_mfma_f32_16x16x32_bf16(wih_l[0], xf0, acc, 0, 0, 0);
        acc = __builtin_amdgcn_mfma_f32_16x16x32_bf16(wih_l[1], xf1, acc, 0, 0, 0);
        acc = __builtin_amdgcn_mfma_f32_16x16x32_bf16(whh_l[0], hf0, acc, 0, 0, 0);
        acc = __builtin_amdgcn_mfma_f32_16x16x32_bf16(whh_l[1], hf1, acc, 0, 0, 0);
        acc = __builtin_amdgcn_mfma_f32_16x16x32_bf16(whh_l[2], hf2, acc, 0, 0, 0);
        acc = __builtin_amdgcn_mfma_f32_16x16x32_bf16(whh_l[3], hf3, acc, 0, 0, 0);
        acc = __builtin_amdgcn_mfma_f32_16x16x32_bf16(wih_h[0], xf0, acc, 0, 0, 0);
        acc = __builtin_amdgcn_mfma_f32_16x16x32_bf16(wih_h[1], xf1, acc, 0, 0, 0);
        acc = __builtin_amdgcn_mfma_f32_16x16x32_bf16(whh_h[0], hf0, acc, 0, 0, 0);
        acc = __builtin_amdgcn_mfma_f32_16x16x32_bf16(whh_h[1], hf1, acc, 0, 0, 0);
        acc = __builtin_amdgcn_mfma_f32_16x16x32_bf16(whh_h[2], hf2, acc, 0, 0, 0);
        acc = __builtin_amdgcn_mfma_f32_16x16x32_bf16(whh_h[3], hf3, acc, 0, 0, 0);

        // C layout: col = lane&15 = b ; row = 4*kg + i = hidden unit (4 consecutive n)
        float t0 = tanh_fast(acc[0]);
        float t1 = tanh_fast(acc[1]);
        float t2 = tanh_fast(acc[2]);
        float t3 = tanh_fast(acc[3]);

        if (t == S_LEN - 1) {
            f32x4 o = {t0, t1, t2, t3};
            *(f32x4*)(out + ((size_t)b0 + col) * NHID + 16 * w + 4 * kg) = o;
        } else {
            s16x4 hb = { (short)f2bf(t0), (short)f2bf(t1),
                         (short)f2bf(t2), (short)f2bf(t3) };
            *(s16x4*)&hbuf[(t + 1) & 1][col][16 * w + 4 * kg] = hb;  // ds_write_b64
        }
        __syncthreads();  // write(t+1-buf) -> read(t+1) ordering; 1 barrier/step
    };

    for (int t = 0; t < S_LEN; t += 2) {
        step(t,     a0, a1, a2, a3);
        step(t + 1, c0, c1, c2, c3);
    }
}

extern "C" void kernel_launch(void* const* d_in, const int* in_sizes, int n_in,
                              void* d_out, int out_size, void* d_ws, size_t ws_size,
                              hipStream_t stream) {
    const float* x    = (const float*)d_in[0];
    const float* W_ih = (const float*)d_in[1];
    const float* b_ih = (const float*)d_in[2];
    const float* W_hh = (const float*)d_in[3];
    const float* b_hh = (const float*)d_in[4];
    float* out = (float*)d_out;

    dim3 grid(BATCH / BT);
    dim3 block(512);
    rnn_kernel<<<grid, block, 0, stream>>>(x, W_ih, b_ih, W_hh, b_hh, out);
}

// Round 2
// 927.247 us; speedup vs baseline: 1.5519x; 1.5519x over previous
//
#include <hip/hip_runtime.h>

#define S_LEN 1024
#define BATCH 4096
#define NIN 64
#define NHID 128
#define BT 16      // batch rows per block
#define NPAD 136   // padded h row stride (bf16 elems): stride 68 dwords == 4 mod 32 banks

typedef __attribute__((ext_vector_type(8))) short bf16x8;
typedef __attribute__((ext_vector_type(4))) float f32x4;
typedef __attribute__((ext_vector_type(4))) short s16x4;

__device__ __forceinline__ unsigned short f2bf(float f) {
    union { float f; unsigned u; } v; v.f = f;
    unsigned r = v.u + 0x7FFFu + ((v.u >> 16) & 1u);   // RNE
    return (unsigned short)(r >> 16);
}
__device__ __forceinline__ float bf2f(unsigned short h) {
    union { float f; unsigned u; } v; v.u = ((unsigned)h) << 16;
    return v.f;
}
__device__ __forceinline__ float tanh_fast(float z) {
    // tanh(z) = (e^{2z}-1)/(e^{2z}+1); e^{2z} = 2^(z*2/ln2)
    float u = __builtin_amdgcn_exp2f(z * 2.885390081777927f);
    return (u - 1.0f) * __builtin_amdgcn_rcpf(u + 1.0f);
}

// Barrier WITHOUT vmcnt(0) drain: only LDS ops (lgkm) must be visible across
// the barrier; in-flight global x-prefetch loads are lane-private registers.
// "memory" clobber fences LDS read/write movement across this point.
__device__ __forceinline__ void lds_barrier() {
    asm volatile("s_waitcnt lgkmcnt(0)\n\ts_barrier" ::: "memory");
}

__global__ __launch_bounds__(512, 2)
void rnn_kernel(const float* __restrict__ x,
                const float* __restrict__ W_ih,
                const float* __restrict__ b_ih,
                const float* __restrict__ W_hh,
                const float* __restrict__ b_hh,
                float* __restrict__ out)
{
    __shared__ short hbuf[2][BT][NPAD];

    const int tid  = threadIdx.x;
    const int w    = tid >> 6;    // wave 0..7, owns hidden rows [16w,16w+16)
    const int lane = tid & 63;
    const int col  = lane & 15;   // batch index within tile (MFMA B-op col / C col)
    const int kg   = lane >> 4;   // k-group 0..3

    const int bb0 = blockIdx.x * BT;

    // zero h double-buffer (h_0 = 0)
    for (int i = tid; i < 2 * BT * NPAD; i += 512) ((short*)hbuf)[i] = 0;

    // ---- persistent weight fragments (MFMA A-operand), W = hi + lo bf16 split
    const int nrow = 16 * w + col;
    bf16x8 wih_h[2], wih_l[2], whh_h[4], whh_l[4];
    #pragma unroll
    for (int kk = 0; kk < 2; ++kk) {
        const float* p = W_ih + nrow * NIN + kk * 32 + kg * 8;
        #pragma unroll
        for (int j = 0; j < 8; ++j) {
            float f = p[j];
            unsigned short hi = f2bf(f);
            wih_h[kk][j] = (short)hi;
            wih_l[kk][j] = (short)f2bf(f - bf2f(hi));
        }
    }
    #pragma unroll
    for (int kk = 0; kk < 4; ++kk) {
        const float* p = W_hh + nrow * NHID + kk * 32 + kg * 8;
        #pragma unroll
        for (int j = 0; j < 8; ++j) {
            float f = p[j];
            unsigned short hi = f2bf(f);
            whh_h[kk][j] = (short)hi;
            whh_l[kk][j] = (short)f2bf(f - bf2f(hi));
        }
    }

    // bias for this lane's 4 output hidden units n = 16w + 4kg + i
    f32x4 biasv;
    {
        f32x4 bi = *(const f32x4*)(b_ih + 16 * w + 4 * kg);
        f32x4 bh = *(const f32x4*)(b_hh + 16 * w + 4 * kg);
        biasv = bi + bh;
    }

    // x B-operand: lane reads x_t[b=col][k = 32*kk + 8*kg + j]
    const float* xlane = x + ((size_t)bb0 + col) * NIN + kg * 8;

    auto loadStage = [&](f32x4& v0, f32x4& v1, f32x4& v2, f32x4& v3, int t) {
        if (t < S_LEN) {
            const float* p = xlane + (size_t)t * (BATCH * NIN);
            v0 = *(const f32x4*)(p);      v1 = *(const f32x4*)(p + 4);
            v2 = *(const f32x4*)(p + 32); v3 = *(const f32x4*)(p + 36);
        }
    };

    // xp(t) = b_ih + b_hh + W_ih(hi+lo) @ x_t  — independent of h, off-critical
    auto computeXP = [&](const f32x4& v0, const f32x4& v1,
                         const f32x4& v2, const f32x4& v3) -> f32x4 {
        bf16x8 xf0, xf1;
        #pragma unroll
        for (int j = 0; j < 4; ++j) {
            xf0[j]     = (short)f2bf(v0[j]);
            xf0[j + 4] = (short)f2bf(v1[j]);
            xf1[j]     = (short)f2bf(v2[j]);
            xf1[j + 4] = (short)f2bf(v3[j]);
        }
        f32x4 xp = biasv;
        xp = __builtin_amdgcn_mfma_f32_16x16x32_bf16(wih_h[0], xf0, xp, 0, 0, 0);
        xp = __builtin_amdgcn_mfma_f32_16x16x32_bf16(wih_h[1], xf1, xp, 0, 0, 0);
        xp = __builtin_amdgcn_mfma_f32_16x16x32_bf16(wih_l[0], xf0, xp, 0, 0, 0);
        xp = __builtin_amdgcn_mfma_f32_16x16x32_bf16(wih_l[1], xf1, xp, 0, 0, 0);
        return xp;
    };

    auto step = [&](int t, f32x4& s0, f32x4& s1, f32x4& s2, f32x4& s3,
                    const f32x4& xp_cur, f32x4& xp_next) {
        // ---- critical path: h(t) -> h(t+1)
        const short* hrow = &hbuf[t & 1][col][0];
        bf16x8 hf0 = *(const bf16x8*)(hrow +  0 + kg * 8);
        bf16x8 hf1 = *(const bf16x8*)(hrow + 32 + kg * 8);
        bf16x8 hf2 = *(const bf16x8*)(hrow + 64 + kg * 8);
        bf16x8 hf3 = *(const bf16x8*)(hrow + 96 + kg * 8);

        f32x4 acc_a = xp_cur;
        f32x4 acc_b = {0.f, 0.f, 0.f, 0.f};
        acc_a = __builtin_amdgcn_mfma_f32_16x16x32_bf16(whh_h[0], hf0, acc_a, 0, 0, 0);
        acc_b = __builtin_amdgcn_mfma_f32_16x16x32_bf16(whh_l[0], hf0, acc_b, 0, 0, 0);
        acc_a = __builtin_amdgcn_mfma_f32_16x16x32_bf16(whh_h[1], hf1, acc_a, 0, 0, 0);
        acc_b = __builtin_amdgcn_mfma_f32_16x16x32_bf16(whh_l[1], hf1, acc_b, 0, 0, 0);
        acc_a = __builtin_amdgcn_mfma_f32_16x16x32_bf16(whh_h[2], hf2, acc_a, 0, 0, 0);
        acc_b = __builtin_amdgcn_mfma_f32_16x16x32_bf16(whh_l[2], hf2, acc_b, 0, 0, 0);
        acc_a = __builtin_amdgcn_mfma_f32_16x16x32_bf16(whh_h[3], hf3, acc_a, 0, 0, 0);
        acc_b = __builtin_amdgcn_mfma_f32_16x16x32_bf16(whh_l[3], hf3, acc_b, 0, 0, 0);
        f32x4 acc = acc_a + acc_b;

        // C layout: col = lane&15 = b ; row = 4*kg + i = hidden unit
        float t0 = tanh_fast(acc[0]);
        float t1 = tanh_fast(acc[1]);
        float t2 = tanh_fast(acc[2]);
        float t3 = tanh_fast(acc[3]);

        if (t == S_LEN - 1) {
            f32x4 o = {t0, t1, t2, t3};
            *(f32x4*)(out + ((size_t)bb0 + col) * NHID + 16 * w + 4 * kg) = o;
        } else {
            s16x4 hb = { (short)f2bf(t0), (short)f2bf(t1),
                         (short)f2bf(t2), (short)f2bf(t3) };
            *(s16x4*)&hbuf[(t + 1) & 1][col][16 * w + 4 * kg] = hb;  // ds_write_b64
        }

        // ---- off-critical: xp for t+1, then refill this stage with x[t+5]
        if (t + 1 < S_LEN) {
            xp_next = computeXP(s0, s1, s2, s3);
            loadStage(s0, s1, s2, s3, t + 5);
        }

        lds_barrier();   // lgkmcnt(0) + s_barrier — NO vmcnt drain
    };

    // ---- prologue: 4-deep x prefetch pipeline
    f32x4 a0, a1, a2, a3, e0, e1, e2, e3, c0, c1, c2, c3, d0, d1, d2, d3;
    loadStage(a0, a1, a2, a3, 0);
    loadStage(e0, e1, e2, e3, 1);
    loadStage(c0, c1, c2, c3, 2);
    loadStage(d0, d1, d2, d3, 3);
    f32x4 xp_a = computeXP(a0, a1, a2, a3);   // xp(0)
    loadStage(a0, a1, a2, a3, 4);             // refill consumed stage
    f32x4 xp_b;
    __syncthreads();   // one-time: covers hbuf zero-init (vmcnt drain harmless here)

    for (int t = 0; t < S_LEN; t += 4) {
        step(t + 0, e0, e1, e2, e3, xp_a, xp_b);
        step(t + 1, c0, c1, c2, c3, xp_b, xp_a);
        step(t + 2, d0, d1, d2, d3, xp_a, xp_b);
        step(t + 3, a0, a1, a2, a3, xp_b, xp_a);
    }
}

extern "C" void kernel_launch(void* const* d_in, const int* in_sizes, int n_in,
                              void* d_out, int out_size, void* d_ws, size_t ws_size,
                              hipStream_t stream) {
    const float* x    = (const float*)d_in[0];
    const float* W_ih = (const float*)d_in[1];
    const float* b_ih = (const float*)d_in[2];
    const float* W_hh = (const float*)d_in[3];
    const float* b_hh = (const float*)d_in[4];
    float* out = (float*)d_out;

    dim3 grid(BATCH / BT);
    dim3 block(512);
    rnn_kernel<<<grid, block, 0, stream>>>(x, W_ih, b_ih, W_hh, b_hh, out);
}

// Round 3
// 896.611 us; speedup vs baseline: 1.6049x; 1.0342x over previous
//
#include <hip/hip_runtime.h>

#define S_LEN 1024
#define BATCH 4096
#define NIN 64
#define NHID 128
#define BT 16      // batch rows per block
#define NPAD 136   // padded h row stride (bf16 elems)

typedef __attribute__((ext_vector_type(8))) short bf16x8;
typedef __attribute__((ext_vector_type(4))) float f32x4;

__device__ __forceinline__ unsigned short f2bf(float f) {
    union { float f; unsigned u; } v; v.f = f;
    unsigned r = v.u + 0x7FFFu + ((v.u >> 16) & 1u);   // RNE
    return (unsigned short)(r >> 16);
}
__device__ __forceinline__ float bf2f(unsigned short h) {
    union { float f; unsigned u; } v; v.u = ((unsigned)h) << 16;
    return v.f;
}
// HW packed f32->bf16 (RNE): 2 values per instruction, vs ~3 VALU ops/value scalar
__device__ __forceinline__ unsigned cvt_pk(float lo, float hi) {
    unsigned r;
    asm("v_cvt_pk_bf16_f32 %0, %1, %2" : "=v"(r) : "v"(lo), "v"(hi));
    return r;
}
__device__ __forceinline__ float tanh_fast(float z) {
    // tanh(z) = (e^{2z}-1)/(e^{2z}+1); |z| bounded ~5 here, no overflow
    float u = __builtin_amdgcn_exp2f(z * 2.885390081777927f);
    return (u - 1.0f) * __builtin_amdgcn_rcpf(u + 1.0f);
}
// Barrier WITHOUT vmcnt(0) drain (x prefetch stays in flight across steps)
__device__ __forceinline__ void lds_barrier() {
    asm volatile("s_waitcnt lgkmcnt(0)\n\ts_barrier" ::: "memory");
}

__global__ __launch_bounds__(512, 2)
void rnn_kernel(const float* __restrict__ x,
                const float* __restrict__ W_ih,
                const float* __restrict__ b_ih,
                const float* __restrict__ W_hh,
                const float* __restrict__ b_hh,
                float* __restrict__ out)
{
    __shared__ short hbuf[2][BT][NPAD];

    const int tid  = threadIdx.x;
    const int w    = tid >> 6;    // wave: hidden rows [16w, 16w+16)
    const int lane = tid & 63;
    const int col  = lane & 15;   // batch index within tile
    const int kg   = lane >> 4;   // k-group 0..3

    const int bb0 = blockIdx.x * BT;

    // zero buf[0] only (h_0 = 0); buf[1] fully written at t=0 before first read
    for (int i = tid; i < BT * NPAD / 2; i += 512) ((int*)hbuf)[i] = 0;

    // ---- persistent weight fragments. W_hh = hi+lo bf16 split; W_ih hi only.
    const int nrow = 16 * w + col;
    bf16x8 wih_h[2], whh_h[4], whh_l[4];
    #pragma unroll
    for (int kk = 0; kk < 2; ++kk) {
        const float* p = W_ih + nrow * NIN + kk * 32 + kg * 8;
        #pragma unroll
        for (int j = 0; j < 8; ++j) wih_h[kk][j] = (short)f2bf(p[j]);
    }
    #pragma unroll
    for (int kk = 0; kk < 4; ++kk) {
        const float* p = W_hh + nrow * NHID + kk * 32 + kg * 8;
        #pragma unroll
        for (int j = 0; j < 8; ++j) {
            float f = p[j];
            unsigned short hi = f2bf(f);
            whh_h[kk][j] = (short)hi;
            whh_l[kk][j] = (short)f2bf(f - bf2f(hi));
        }
    }

    f32x4 biasv;
    {
        f32x4 bi = *(const f32x4*)(b_ih + 16 * w + 4 * kg);
        f32x4 bh = *(const f32x4*)(b_hh + 16 * w + 4 * kg);
        biasv = bi + bh;
    }

    const float* xlane = x + ((size_t)bb0 + col) * NIN + kg * 8;

    auto loadStage = [&](f32x4& v0, f32x4& v1, f32x4& v2, f32x4& v3, int t) {
        if (t < S_LEN) {
            const float* p = xlane + (size_t)t * (BATCH * NIN);
            v0 = *(const f32x4*)(p);      v1 = *(const f32x4*)(p + 4);
            v2 = *(const f32x4*)(p + 32); v3 = *(const f32x4*)(p + 36);
        }
    };

    // xp(t) = b_ih + b_hh + W_ih_hi @ x_t  (off the h critical path)
    auto computeXP = [&](const f32x4& v0, const f32x4& v1,
                         const f32x4& v2, const f32x4& v3) -> f32x4 {
        union { bf16x8 v; unsigned u[4]; } xf0, xf1;
        xf0.u[0] = cvt_pk(v0[0], v0[1]); xf0.u[1] = cvt_pk(v0[2], v0[3]);
        xf0.u[2] = cvt_pk(v1[0], v1[1]); xf0.u[3] = cvt_pk(v1[2], v1[3]);
        xf1.u[0] = cvt_pk(v2[0], v2[1]); xf1.u[1] = cvt_pk(v2[2], v2[3]);
        xf1.u[2] = cvt_pk(v3[0], v3[1]); xf1.u[3] = cvt_pk(v3[2], v3[3]);
        f32x4 xp = biasv;
        xp = __builtin_amdgcn_mfma_f32_16x16x32_bf16(wih_h[0], xf0.v, xp, 0, 0, 0);
        xp = __builtin_amdgcn_mfma_f32_16x16x32_bf16(wih_h[1], xf1.v, xp, 0, 0, 0);
        return xp;
    };

    auto step = [&](int t, f32x4& s0, f32x4& s1, f32x4& s2, f32x4& s3,
                    const f32x4& xp_cur, f32x4& xp_next) {
        // issue h reads first; latency hides under xp/prefetch below
        const short* hrow = &hbuf[t & 1][col][0];
        bf16x8 hf0 = *(const bf16x8*)(hrow +  0 + kg * 8);
        bf16x8 hf1 = *(const bf16x8*)(hrow + 32 + kg * 8);
        bf16x8 hf2 = *(const bf16x8*)(hrow + 64 + kg * 8);
        bf16x8 hf3 = *(const bf16x8*)(hrow + 96 + kg * 8);

        if (t + 1 < S_LEN) {
            xp_next = computeXP(s0, s1, s2, s3);
            loadStage(s0, s1, s2, s3, t + 5);
        }

        // 4 independent depth-2 MFMA chains, tree-combined
        f32x4 z4 = {0.f, 0.f, 0.f, 0.f};
        f32x4 cA = xp_cur, cB = z4, cC = z4, cD = z4;
        cA = __builtin_amdgcn_mfma_f32_16x16x32_bf16(whh_h[0], hf0, cA, 0, 0, 0);
        cC = __builtin_amdgcn_mfma_f32_16x16x32_bf16(whh_l[0], hf0, cC, 0, 0, 0);
        cB = __builtin_amdgcn_mfma_f32_16x16x32_bf16(whh_h[2], hf2, cB, 0, 0, 0);
        cD = __builtin_amdgcn_mfma_f32_16x16x32_bf16(whh_l[2], hf2, cD, 0, 0, 0);
        cA = __builtin_amdgcn_mfma_f32_16x16x32_bf16(whh_h[1], hf1, cA, 0, 0, 0);
        cC = __builtin_amdgcn_mfma_f32_16x16x32_bf16(whh_l[1], hf1, cC, 0, 0, 0);
        cB = __builtin_amdgcn_mfma_f32_16x16x32_bf16(whh_h[3], hf3, cB, 0, 0, 0);
        cD = __builtin_amdgcn_mfma_f32_16x16x32_bf16(whh_l[3], hf3, cD, 0, 0, 0);
        f32x4 acc = (cA + cB) + (cC + cD);

        float t0 = tanh_fast(acc[0]);
        float t1 = tanh_fast(acc[1]);
        float t2 = tanh_fast(acc[2]);
        float t3 = tanh_fast(acc[3]);

        if (t == S_LEN - 1) {
            f32x4 o = {t0, t1, t2, t3};
            *(f32x4*)(out + ((size_t)bb0 + col) * NHID + 16 * w + 4 * kg) = o;
        } else {
            uint2 hb;
            hb.x = cvt_pk(t0, t1);
            hb.y = cvt_pk(t2, t3);
            *(uint2*)&hbuf[(t + 1) & 1][col][16 * w + 4 * kg] = hb;  // ds_write_b64
        }
        lds_barrier();
    };

    // ---- prologue: 4-deep x prefetch pipeline
    f32x4 a0, a1, a2, a3, e0, e1, e2, e3, c0, c1, c2, c3, d0, d1, d2, d3;
    loadStage(a0, a1, a2, a3, 0);
    loadStage(e0, e1, e2, e3, 1);
    loadStage(c0, c1, c2, c3, 2);
    loadStage(d0, d1, d2, d3, 3);
    f32x4 xp_a = computeXP(a0, a1, a2, a3);   // xp(0)
    loadStage(a0, a1, a2, a3, 4);
    f32x4 xp_b;
    __syncthreads();   // one-time: covers hbuf zero-init

    for (int t = 0; t < S_LEN; t += 4) {
        step(t + 0, e0, e1, e2, e3, xp_a, xp_b);
        step(t + 1, c0, c1, c2, c3, xp_b, xp_a);
        step(t + 2, d0, d1, d2, d3, xp_a, xp_b);
        step(t + 3, a0, a1, a2, a3, xp_b, xp_a);
    }
}

extern "C" void kernel_launch(void* const* d_in, const int* in_sizes, int n_in,
                              void* d_out, int out_size, void* d_ws, size_t ws_size,
                              hipStream_t stream) {
    const float* x    = (const float*)d_in[0];
    const float* W_ih = (const float*)d_in[1];
    const float* b_ih = (const float*)d_in[2];
    const float* W_hh = (const float*)d_in[3];
    const float* b_hh = (const float*)d_in[4];
    float* out = (float*)d_out;

    dim3 grid(BATCH / BT);
    dim3 block(512);
    rnn_kernel<<<grid, block, 0, stream>>>(x, W_ih, b_ih, W_hh, b_hh, out);
}